// Round 8
// baseline (396.705 us; speedup 1.0000x reference)
//
#include <hip/hip_runtime.h>
#include <hip/hip_bf16.h>
#include <cstdint>

// Problem: B=4, T=2048, D=1024, H=16, HD=64.
// d_out = [ out (4,2048,1024) | k (4,16,2048,64) | v (4,16,2048,64) ] fp32.

typedef short bf16x8 __attribute__((ext_vector_type(8)));
typedef float f32x4 __attribute__((ext_vector_type(4)));

#define GLDS16(g, l)                                                          \
  __builtin_amdgcn_global_load_lds(                                           \
      (const __attribute__((address_space(1))) void*)(g),                     \
      (__attribute__((address_space(3))) void*)(l), 16, 0, 0)

static __device__ __forceinline__ short f2b(float f) {
  union { float f; unsigned u; } x; x.f = f;
  unsigned r = (x.u + 0x7FFFu + ((x.u >> 16) & 1u)) >> 16;   // RNE
  return (short)r;
}

// single-instruction packed f32->bf16 RNE: dst.lo = a, dst.hi = b
static __device__ __forceinline__ unsigned cvtpk2(float a, float b) {
  unsigned r;
  asm("v_cvt_pk_bf16_f32 %0, %1, %2" : "=v"(r) : "v"(a), "v"(b));
  return r;
}

// One launch converts x (2097152 float4 groups) AND the four weight matrices
// (4 x 262144 groups, dsts contiguous at wqb). Saves a launch gap vs two
// kernels; branch is block-uniform except at region boundaries.
__global__ void cvt_all(const float* __restrict__ x,
                        const float* __restrict__ a, const float* __restrict__ b,
                        const float* __restrict__ c, const float* __restrict__ d,
                        short* __restrict__ xb, short* __restrict__ wb) {
  int i = blockIdx.x * blockDim.x + threadIdx.x;     // 0..3145727
  const float* src;
  short* dst;
  int j;
  if (i < 2097152) {
    src = x; dst = xb; j = i;
  } else {
    int k = i - 2097152;
    int sel = k >> 18;
    src = sel == 0 ? a : sel == 1 ? b : sel == 2 ? c : d;
    dst = wb; j = k;                    // weight dsts contiguous in ws
    src += (size_t)(sel) * 0;           // (sel offset folded into table above)
    j = k;                              // dst index within contiguous region
    // adjust src to the selected matrix's own base index
    int off = k & 262143;
    float4 v = ((const float4*)src)[off];
    short4 o; o.x = f2b(v.x); o.y = f2b(v.y); o.z = f2b(v.z); o.w = f2b(v.w);
    ((short4*)dst)[j] = o;
    return;
  }
  float4 v = ((const float4*)src)[j];
  short4 o; o.x = f2b(v.x); o.y = f2b(v.y); o.z = f2b(v.z); o.w = f2b(v.w);
  ((short4*)dst)[j] = o;
}

// ---------------------------------------------------------------------------
// GEMM core: 128x128 tile, BK=32, 4 waves, T4 counted-vmcnt 3-deep pipeline.
// (verified passing, rounds 4/5/7 — unchanged)
// ---------------------------------------------------------------------------
#define PIPE_STEP(BUF)                                                        \
  {                                                                          \
    asm volatile("s_waitcnt vmcnt(4) lgkmcnt(0)" ::: "memory");              \
    __builtin_amdgcn_s_barrier();                                            \
    __builtin_amdgcn_sched_barrier(0);                                       \
    stage((((BUF) + 2) % 3), (tile + 2) * 32);                               \
    compute(BUF);                                                            \
    ++tile;                                                                  \
  }

#define PIPE_TAIL()                                                          \
  asm volatile("s_waitcnt vmcnt(4) lgkmcnt(0)" ::: "memory");                \
  __builtin_amdgcn_s_barrier();                                              \
  __builtin_amdgcn_sched_barrier(0);                                         \
  compute(0); /* tile 30 */                                                  \
  asm volatile("s_waitcnt vmcnt(0) lgkmcnt(0)" ::: "memory");                \
  __builtin_amdgcn_s_barrier();                                              \
  __builtin_amdgcn_sched_barrier(0);                                         \
  compute(1); /* tile 31 */

// Fused Q/K/V projection. blockIdx.x 0..7 -> Q, 8..15 -> K, 16..23 -> V.
__global__ __launch_bounds__(256) void gemm_qkv(
    const short* __restrict__ A,
    const short* __restrict__ W0, const short* __restrict__ W1, const short* __restrict__ W2,
    const float* __restrict__ b0, const float* __restrict__ b1, const float* __restrict__ b2,
    float* __restrict__ kf, float* __restrict__ vf,
    short* __restrict__ qbo, short* __restrict__ kbo, short* __restrict__ vtbo) {
  __shared__ short SM[24576];                              // 48 KB: A bufs 0..2, B bufs 0..2
  const int t = threadIdx.x;
  const int lane = t & 63;
  const int w = t >> 6;
  const int wm = w >> 1, wn = w & 1;
  const int quad = lane >> 4, l15 = lane & 15;
  const int bm = blockIdx.y;
  const int sel = blockIdx.x >> 3, bn = blockIdx.x & 7;    // block-uniform branch
  const short* Bm = sel == 0 ? W0 : (sel == 1 ? W1 : W2);
  const float* bias = sel == 0 ? b0 : (sel == 1 ? b1 : b2);

  f32x4 acc[4][4];
  for (int i = 0; i < 4; i++)
    for (int j = 0; j < 4; j++) acc[i][j] = (f32x4){0.f, 0.f, 0.f, 0.f};

  const int c0 = t, c1 = t + 256;
  const int r0 = c0 >> 2, cc0 = c0 & 3;
  const int r1 = c1 >> 2, cc1 = c1 & 3;
  const short* Abase = A + (size_t)bm * 128 * 1024;
  const short* Bbase = Bm + (size_t)bn * 128 * 1024;

  auto stage = [&](int buf, int kk) {
    short* A_ = SM + buf * 4096;
    short* B_ = SM + 12288 + buf * 4096;
    GLDS16(Abase + (size_t)r0 * 1024 + kk + cc0 * 8, A_ + c0 * 8);
    GLDS16(Abase + (size_t)r1 * 1024 + kk + cc1 * 8, A_ + c1 * 8);
    GLDS16(Bbase + (size_t)r0 * 1024 + kk + cc0 * 8, B_ + c0 * 8);
    GLDS16(Bbase + (size_t)r1 * 1024 + kk + cc1 * 8, B_ + c1 * 8);
  };
  auto compute = [&](int buf) {
    const short* A_ = SM + buf * 4096;
    const short* B_ = SM + 12288 + buf * 4096;
    bf16x8 af[4], bfr[4];
    for (int mt = 0; mt < 4; mt++)
      af[mt] = *(const bf16x8*)(A_ + (wm * 64 + mt * 16 + l15) * 32 + quad * 8);
    for (int nt = 0; nt < 4; nt++)
      bfr[nt] = *(const bf16x8*)(B_ + (wn * 64 + nt * 16 + l15) * 32 + quad * 8);
    for (int mt = 0; mt < 4; mt++)
      for (int nt = 0; nt < 4; nt++)
        acc[mt][nt] = __builtin_amdgcn_mfma_f32_16x16x32_bf16(af[mt], bfr[nt], acc[mt][nt], 0, 0, 0);
  };

  stage(0, 0);
  stage(1, 32);
  int tile = 0;
  for (int ii = 0; ii < 10; ++ii) {      // tiles 0..29; stages tiles 2..31
    PIPE_STEP(0) PIPE_STEP(1) PIPE_STEP(2)
  }
  PIPE_TAIL()                             // tiles 30, 31

  if (sel != 2) {
    for (int mt = 0; mt < 4; mt++) {
      const int row_base = bm * 128 + wm * 64 + mt * 16 + quad * 4;
      for (int nt = 0; nt < 4; nt++) {
        const int col = bn * 128 + wn * 64 + nt * 16 + l15;
        const float bb = bias[col];
        for (int r = 0; r < 4; r++) {
          const int row = row_base + r;
          const float v = acc[mt][nt][r] + bb;
          const int b = row >> 11, tt = row & 2047;
          const int h = col >> 6, hi = col & 63;
          const size_t idx = (((size_t)(b * 16 + h)) * 2048 + tt) * 64 + hi;
          if (sel == 0) {
            qbo[idx] = f2b(v);
          } else {
            kf[idx] = v; kbo[idx] = f2b(v);
          }
        }
      }
    }
  } else {
    // V path: f32 out direct; bf16 transpose via LDS (stride 136 shorts).
    short* Tr = SM;                       // 128*136*2 = 34816 B <= 48 KB
    __syncthreads();
    for (int mt = 0; mt < 4; mt++) {
      const int rowb = wm * 64 + mt * 16 + quad * 4;     // local row base
      const int growb = bm * 128 + rowb;
      const int b_ = growb >> 11;
      for (int nt = 0; nt < 4; nt++) {
        const int colL = wn * 64 + nt * 16 + l15;
        const int col = bn * 128 + colL;
        const float bb = bias[col];
        const int h_ = col >> 6, hi_ = col & 63;
        short4 pk;
        for (int r = 0; r < 4; r++) {
          const float v = acc[mt][nt][r] + bb;
          const int tt = (growb + r) & 2047;
          vf[(((size_t)(b_ * 16 + h_)) * 2048 + tt) * 64 + hi_] = v;
          ((short*)&pk)[r] = f2b(v);
        }
        *(short4*)&Tr[colL * 136 + rowb] = pk;
      }
    }
    __syncthreads();
    const int c = t & 127, half = t >> 7;
    const int gcol = bn * 128 + c;
    const int h_ = gcol >> 6, hi_ = gcol & 63;
    for (int j = 0; j < 8; j++) {
      const int chunk = half * 8 + j;
      const int row0 = bm * 128 + chunk * 8;
      const int b_ = row0 >> 11, tt = row0 & 2047;
      bf16x8 val = *(const bf16x8*)&Tr[c * 136 + chunk * 8];
      *(bf16x8*)&vtbo[(((size_t)(b_ * 16 + h_)) * 64 + hi_) * 2048 + tt] = val;
    }
  }
}

// Output projection: C[8192][1024] = attb @ Wo^T + bo, same T4 pipeline.
__global__ __launch_bounds__(256) void gemm_o(
    const short* __restrict__ A, const short* __restrict__ Bm,
    const float* __restrict__ bias, float* __restrict__ out_f) {
  __shared__ short SM[24576];
  const int t = threadIdx.x;
  const int lane = t & 63;
  const int w = t >> 6;
  const int wm = w >> 1, wn = w & 1;
  const int quad = lane >> 4, l15 = lane & 15;
  const int bm = blockIdx.y, bn = blockIdx.x;

  f32x4 acc[4][4];
  for (int i = 0; i < 4; i++)
    for (int j = 0; j < 4; j++) acc[i][j] = (f32x4){0.f, 0.f, 0.f, 0.f};

  const int c0 = t, c1 = t + 256;
  const int r0 = c0 >> 2, cc0 = c0 & 3;
  const int r1 = c1 >> 2, cc1 = c1 & 3;
  const short* Abase = A + (size_t)bm * 128 * 1024;
  const short* Bbase = Bm + (size_t)bn * 128 * 1024;

  auto stage = [&](int buf, int kk) {
    short* A_ = SM + buf * 4096;
    short* B_ = SM + 12288 + buf * 4096;
    GLDS16(Abase + (size_t)r0 * 1024 + kk + cc0 * 8, A_ + c0 * 8);
    GLDS16(Abase + (size_t)r1 * 1024 + kk + cc1 * 8, A_ + c1 * 8);
    GLDS16(Bbase + (size_t)r0 * 1024 + kk + cc0 * 8, B_ + c0 * 8);
    GLDS16(Bbase + (size_t)r1 * 1024 + kk + cc1 * 8, B_ + c1 * 8);
  };
  auto compute = [&](int buf) {
    const short* A_ = SM + buf * 4096;
    const short* B_ = SM + 12288 + buf * 4096;
    bf16x8 af[4], bfr[4];
    for (int mt = 0; mt < 4; mt++)
      af[mt] = *(const bf16x8*)(A_ + (wm * 64 + mt * 16 + l15) * 32 + quad * 8);
    for (int nt = 0; nt < 4; nt++)
      bfr[nt] = *(const bf16x8*)(B_ + (wn * 64 + nt * 16 + l15) * 32 + quad * 8);
    for (int mt = 0; mt < 4; mt++)
      for (int nt = 0; nt < 4; nt++)
        acc[mt][nt] = __builtin_amdgcn_mfma_f32_16x16x32_bf16(af[mt], bfr[nt], acc[mt][nt], 0, 0, 0);
  };

  stage(0, 0);
  stage(1, 32);
  int tile = 0;
  for (int ii = 0; ii < 10; ++ii) {
    PIPE_STEP(0) PIPE_STEP(1) PIPE_STEP(2)
  }
  PIPE_TAIL()

  for (int mt = 0; mt < 4; mt++) {
    const int row_base = bm * 128 + wm * 64 + mt * 16 + quad * 4;
    for (int nt = 0; nt < 4; nt++) {
      const int col = bn * 128 + wn * 64 + nt * 16 + l15;
      const float bb = bias[col];
      for (int r = 0; r < 4; r++) {
        const int row = row_base + r;
        out_f[(size_t)row * 1024 + col] = acc[mt][nt][r] + bb;
      }
    }
  }
}

// Flash attention — byte-identical to the round-4 champion (96 us verified):
//  * Paired causal strips (qt, 31-qt), processed SEQUENTIALLY: uniform cost
//    per (strip,jt) iteration keeps all blocks streaming K/V tiles in
//    lockstep -> L2 hit ~88% on re-staged tiles (round-7 lesson: fused-pair
//    variants desynchronize blocks and collapse L2 reuse).
//  * 1024 uniform blocks = 4/CU; P overlays Ks (32 KB LDS).
//  * RAW-score softmax, exact defer-rescale, XCD head remap.
__global__ __launch_bounds__(256, 4) void attn_fwd(
    const short* __restrict__ Qb, const short* __restrict__ Kb,
    const short* __restrict__ VTb, short* __restrict__ Ob) {
  __shared__ short Ks[128 * 64];        // 16 KB; doubles as per-wave P after QK barrier
  __shared__ short VTs[64 * 128];       // 16 KB
  const int t = threadIdx.x;
  const int w = t >> 6;
  const int lane = t & 63;
  const int quad = lane >> 4, l15 = lane & 15;

  const int L = blockIdx.x + (blockIdx.y << 4);          // 0..1023
  const int work = ((L & 7) << 7) + (L >> 3);            // XCD k -> bh in [8k,8k+8)
  const int bh = work >> 4;
  const int base = work & 15;
  const int b = bh >> 4, h = bh & 15;

  const short* Qh = Qb + (size_t)bh * 2048 * 64;
  const short* Kh = Kb + (size_t)bh * 2048 * 64;
  const short* VTh = VTb + (size_t)bh * 64 * 2048;
  unsigned* Pd = (unsigned*)Ks + w * 1024;               // wave-private 4 KB
  const int swz = (l15 & 7) << 2;
  const float sscale = 0.125f * 1.4426950408889634f;     // hd^-0.5 * log2(e)

  for (int s = 0; s < 2; ++s) {
    const int qt = s ? (31 - base) : base;               // 17 tiles total per block
    const int q0 = qt * 64 + w * 16;
    const bf16x8 qf0 = *(const bf16x8*)(Qh + (q0 + l15) * 64 + quad * 8);
    const bf16x8 qf1 = *(const bf16x8*)(Qh + (q0 + l15) * 64 + quad * 8 + 32);

    float m_q = -1e30f, l_q = 0.f;
    f32x4 o[4];
    for (int nt = 0; nt < 4; nt++) o[nt] = (f32x4){0.f, 0.f, 0.f, 0.f};
    const int ntile = (qt >> 1) + 1;

    for (int jt = 0; jt < ntile; ++jt) {
      const int j0 = jt << 7;
      __syncthreads();   // previous tile's P/PV readers done
      for (int rr = 0; rr < 4; rr++) {
        const int c = rr * 256 + t;
        const int row = c >> 3, colL = c & 7;
        const int colg = colL ^ (row & 7);
        GLDS16(Kh + (size_t)(j0 + row) * 64 + colg * 8, &Ks[c * 8]);
      }
      for (int rr = 0; rr < 4; rr++) {
        const int c = rr * 256 + t;
        const int row = c >> 4, colL = c & 15;
        const int colg = colL ^ (row & 7);
        GLDS16(VTh + (size_t)row * 2048 + j0 + colg * 8, &VTs[c * 8]);
      }
      __syncthreads();   // staging complete (vmcnt drained)

      float sv[8][4];    // RAW scores (scale folded into exp arg later)
      for (int si = 0; si < 8; ++si) {
        const int r = si * 16 + l15;
        bf16x8 kf0 = *(const bf16x8*)&Ks[(r * 8 + (quad ^ (r & 7))) * 8];
        bf16x8 kf1 = *(const bf16x8*)&Ks[(r * 8 + ((quad ^ 4) ^ (r & 7))) * 8];
        f32x4 z = (f32x4){0.f, 0.f, 0.f, 0.f};
        z = __builtin_amdgcn_mfma_f32_16x16x32_bf16(kf0, qf0, z, 0, 0, 0);
        z = __builtin_amdgcn_mfma_f32_16x16x32_bf16(kf1, qf1, z, 0, 0, 0);
        for (int r4 = 0; r4 < 4; r4++) sv[si][r4] = z[r4];
      }
      if (jt == ntile - 1) {                              // diagonal tile masks
        const int qg = q0 + l15;
        for (int si = 0; si < 8; si++) {
          const int kbase = j0 + si * 16 + quad * 4;
          for (int r4 = 0; r4 < 4; r4++)
            if (kbase + r4 > qg) sv[si][r4] = -1e30f;
        }
      }
      float vmax = fmaxf(fmaxf(sv[0][0], sv[0][1]), fmaxf(sv[0][2], sv[0][3]));
      for (int si = 1; si < 8; si++) {
        float m2 = fmaxf(fmaxf(sv[si][0], sv[si][1]), fmaxf(sv[si][2], sv[si][3]));
        vmax = fmaxf(vmax, m2);
      }
      vmax = fmaxf(vmax, __shfl_xor(vmax, 16));
      vmax = fmaxf(vmax, __shfl_xor(vmax, 32));
      const float mn = fmaxf(m_q, vmax);
      if (__any(vmax > m_q)) {           // exact skip: otherwise alpha==1 for all lanes
        const float alpha = __builtin_amdgcn_exp2f((m_q - mn) * sscale);
        l_q *= alpha;
        float ar[4];
        for (int r4 = 0; r4 < 4; r4++) ar[r4] = __shfl(alpha, quad * 4 + r4);
        for (int nt = 0; nt < 4; nt++)
          for (int r4 = 0; r4 < 4; r4++) o[nt][r4] *= ar[r4];
      }
      m_q = mn;
      __syncthreads();   // all waves done reading Ks -> safe to overlay P

      const float negmns = -mn * sscale;
      float ssum = 0.f;
      for (int si = 0; si < 8; si++) {
        float p0 = __builtin_amdgcn_exp2f(fmaf(sv[si][0], sscale, negmns));
        float p1 = __builtin_amdgcn_exp2f(fmaf(sv[si][1], sscale, negmns));
        float p2 = __builtin_amdgcn_exp2f(fmaf(sv[si][2], sscale, negmns));
        float p3 = __builtin_amdgcn_exp2f(fmaf(sv[si][3], sscale, negmns));
        ssum += (p0 + p1) + (p2 + p3);
        uint2 pk; pk.x = cvtpk2(p0, p1); pk.y = cvtpk2(p2, p3);
        *(uint2*)(Pd + l15 * 64 + ((si * 8 + quad * 2) ^ swz)) = pk;
      }
      ssum += __shfl_xor(ssum, 16);
      ssum += __shfl_xor(ssum, 32);
      l_q += ssum;       // alpha already applied inside the rescale branch

      for (int kc = 0; kc < 4; kc++) {
        bf16x8 pf = *(const bf16x8*)(Pd + l15 * 64 + ((kc * 16 + quad * 4) ^ swz));
        for (int nt = 0; nt < 4; nt++) {
          const int rv = nt * 16 + l15;
          bf16x8 vf = *(const bf16x8*)&VTs[(rv * 16 + ((kc * 4 + quad) ^ (rv & 7))) * 8];
          o[nt] = __builtin_amdgcn_mfma_f32_16x16x32_bf16(pf, vf, o[nt], 0, 0, 0);
        }
      }
    }

    float lr[4], ri[4];
    for (int r4 = 0; r4 < 4; r4++) lr[r4] = __shfl(l_q, quad * 4 + r4);
    for (int r4 = 0; r4 < 4; r4++) ri[r4] = __builtin_amdgcn_rcpf(lr[r4]);
    for (int nt = 0; nt < 4; nt++) {
      const int col = h * 64 + nt * 16 + l15;
      for (int r4 = 0; r4 < 4; r4++) {
        const int q = q0 + quad * 4 + r4;
        Ob[((size_t)b * 2048 + q) * 1024 + col] = f2b(o[nt][r4] * ri[r4]);
      }
    }
  }
}

extern "C" void kernel_launch(void* const* d_in, const int* in_sizes, int n_in,
                              void* d_out, int out_size, void* d_ws, size_t ws_size,
                              hipStream_t stream) {
  const float* x  = (const float*)d_in[0];
  const float* Wq = (const float*)d_in[1];
  const float* bq = (const float*)d_in[2];
  const float* Wk = (const float*)d_in[3];
  const float* bk = (const float*)d_in[4];
  const float* Wv = (const float*)d_in[5];
  const float* bv = (const float*)d_in[6];
  const float* Wo = (const float*)d_in[7];
  const float* bo = (const float*)d_in[8];

  float* out   = (float*)d_out;
  float* k_out = out + (size_t)8388608;
  float* v_out = out + (size_t)16777216;

  short* ws  = (short*)d_ws;
  short* xb   = ws;                    // 8388608 elems
  short* wqb  = ws + 8388608;          // 1048576 (wq,wk,wv,wo contiguous)
  short* wkb  = ws + 9437184;
  short* wvb  = ws + 10485760;
  short* wob  = ws + 11534336;
  short* qb   = ws + 12582912;         // 8388608 [B,H,T,64]
  short* kb   = ws + 20971520;         // 8388608 [B,H,T,64]
  short* vtb  = ws + 29360128;         // 8388608 [B,H,64,T]
  short* attb = ws + 37748736;         // 8388608 [B*T,1024]

  cvt_all<<<12288, 256, 0, stream>>>(x, Wq, Wk, Wv, Wo, xb, wqb);

  gemm_qkv<<<dim3(24, 64), 256, 0, stream>>>(
      xb, wqb, wkb, wvb, bq, bk, bv, k_out, v_out, qb, kb, vtb);

  attn_fwd<<<dim3(32, 64), 256, 0, stream>>>(qb, kb, vtb, attb);

  gemm_o<<<dim3(8, 64), 256, 0, stream>>>(attb, wob, bo, out);
}

// Round 9
// 325.844 us; speedup vs baseline: 1.2175x; 1.2175x over previous
//
#include <hip/hip_runtime.h>
#include <hip/hip_bf16.h>
#include <cstdint>

// Problem: B=4, T=2048, D=1024, H=16, HD=64.
// d_out = [ out (4,2048,1024) | k (4,16,2048,64) | v (4,16,2048,64) ] fp32.

typedef short bf16x8 __attribute__((ext_vector_type(8)));
typedef float f32x4 __attribute__((ext_vector_type(4)));

#define GLDS16(g, l)                                                          \
  __builtin_amdgcn_global_load_lds(                                           \
      (const __attribute__((address_space(1))) void*)(g),                     \
      (__attribute__((address_space(3))) void*)(l), 16, 0, 0)

static __device__ __forceinline__ short f2b(float f) {
  union { float f; unsigned u; } x; x.f = f;
  unsigned r = (x.u + 0x7FFFu + ((x.u >> 16) & 1u)) >> 16;   // RNE
  return (short)r;
}

// single-instruction packed f32->bf16 RNE: dst.lo = a, dst.hi = b
static __device__ __forceinline__ unsigned cvtpk2(float a, float b) {
  unsigned r;
  asm("v_cvt_pk_bf16_f32 %0, %1, %2" : "=v"(r) : "v"(a), "v"(b));
  return r;
}

// One launch converts x (2097152 float4 groups) AND the four weight matrices
// (4 x 262144 groups, dsts contiguous at wqb).
__global__ void cvt_all(const float* __restrict__ x,
                        const float* __restrict__ a, const float* __restrict__ b,
                        const float* __restrict__ c, const float* __restrict__ d,
                        short* __restrict__ xb, short* __restrict__ wb) {
  int i = blockIdx.x * blockDim.x + threadIdx.x;     // 0..3145727
  if (i < 2097152) {
    float4 v = ((const float4*)x)[i];
    short4 o; o.x = f2b(v.x); o.y = f2b(v.y); o.z = f2b(v.z); o.w = f2b(v.w);
    ((short4*)xb)[i] = o;
  } else {
    int k = i - 2097152;
    int sel = k >> 18;
    const float* src = sel == 0 ? a : sel == 1 ? b : sel == 2 ? c : d;
    int off = k & 262143;
    float4 v = ((const float4*)src)[off];
    short4 o; o.x = f2b(v.x); o.y = f2b(v.y); o.z = f2b(v.z); o.w = f2b(v.w);
    ((short4*)wb)[k] = o;
  }
}

// ---------------------------------------------------------------------------
// GEMM core: 128x128 tile, BK=32, 4 waves, T4 counted-vmcnt 3-deep pipeline.
// (verified passing, rounds 4/5/7/8 — unchanged)
// ---------------------------------------------------------------------------
#define PIPE_STEP(BUF)                                                        \
  {                                                                          \
    asm volatile("s_waitcnt vmcnt(4) lgkmcnt(0)" ::: "memory");              \
    __builtin_amdgcn_s_barrier();                                            \
    __builtin_amdgcn_sched_barrier(0);                                       \
    stage((((BUF) + 2) % 3), (tile + 2) * 32);                               \
    compute(BUF);                                                            \
    ++tile;                                                                  \
  }

#define PIPE_TAIL()                                                          \
  asm volatile("s_waitcnt vmcnt(4) lgkmcnt(0)" ::: "memory");                \
  __builtin_amdgcn_s_barrier();                                              \
  __builtin_amdgcn_sched_barrier(0);                                         \
  compute(0); /* tile 30 */                                                  \
  asm volatile("s_waitcnt vmcnt(0) lgkmcnt(0)" ::: "memory");                \
  __builtin_amdgcn_s_barrier();                                              \
  __builtin_amdgcn_sched_barrier(0);                                         \
  compute(1); /* tile 31 */

// Fused Q/K/V projection. blockIdx.x 0..7 -> Q, 8..15 -> K, 16..23 -> V.
__global__ __launch_bounds__(256) void gemm_qkv(
    const short* __restrict__ A,
    const short* __restrict__ W0, const short* __restrict__ W1, const short* __restrict__ W2,
    const float* __restrict__ b0, const float* __restrict__ b1, const float* __restrict__ b2,
    float* __restrict__ kf, float* __restrict__ vf,
    short* __restrict__ qbo, short* __restrict__ kbo, short* __restrict__ vtbo) {
  __shared__ short SM[24576];                              // 48 KB: A bufs 0..2, B bufs 0..2
  const int t = threadIdx.x;
  const int lane = t & 63;
  const int w = t >> 6;
  const int wm = w >> 1, wn = w & 1;
  const int quad = lane >> 4, l15 = lane & 15;
  const int bm = blockIdx.y;
  const int sel = blockIdx.x >> 3, bn = blockIdx.x & 7;    // block-uniform branch
  const short* Bm = sel == 0 ? W0 : (sel == 1 ? W1 : W2);
  const float* bias = sel == 0 ? b0 : (sel == 1 ? b1 : b2);

  f32x4 acc[4][4];
  for (int i = 0; i < 4; i++)
    for (int j = 0; j < 4; j++) acc[i][j] = (f32x4){0.f, 0.f, 0.f, 0.f};

  const int c0 = t, c1 = t + 256;
  const int r0 = c0 >> 2, cc0 = c0 & 3;
  const int r1 = c1 >> 2, cc1 = c1 & 3;
  const short* Abase = A + (size_t)bm * 128 * 1024;
  const short* Bbase = Bm + (size_t)bn * 128 * 1024;

  auto stage = [&](int buf, int kk) {
    short* A_ = SM + buf * 4096;
    short* B_ = SM + 12288 + buf * 4096;
    GLDS16(Abase + (size_t)r0 * 1024 + kk + cc0 * 8, A_ + c0 * 8);
    GLDS16(Abase + (size_t)r1 * 1024 + kk + cc1 * 8, A_ + c1 * 8);
    GLDS16(Bbase + (size_t)r0 * 1024 + kk + cc0 * 8, B_ + c0 * 8);
    GLDS16(Bbase + (size_t)r1 * 1024 + kk + cc1 * 8, B_ + c1 * 8);
  };
  auto compute = [&](int buf) {
    const short* A_ = SM + buf * 4096;
    const short* B_ = SM + 12288 + buf * 4096;
    bf16x8 af[4], bfr[4];
    for (int mt = 0; mt < 4; mt++)
      af[mt] = *(const bf16x8*)(A_ + (wm * 64 + mt * 16 + l15) * 32 + quad * 8);
    for (int nt = 0; nt < 4; nt++)
      bfr[nt] = *(const bf16x8*)(B_ + (wn * 64 + nt * 16 + l15) * 32 + quad * 8);
    for (int mt = 0; mt < 4; mt++)
      for (int nt = 0; nt < 4; nt++)
        acc[mt][nt] = __builtin_amdgcn_mfma_f32_16x16x32_bf16(af[mt], bfr[nt], acc[mt][nt], 0, 0, 0);
  };

  stage(0, 0);
  stage(1, 32);
  int tile = 0;
  for (int ii = 0; ii < 10; ++ii) {      // tiles 0..29; stages tiles 2..31
    PIPE_STEP(0) PIPE_STEP(1) PIPE_STEP(2)
  }
  PIPE_TAIL()                             // tiles 30, 31

  if (sel != 2) {
    for (int mt = 0; mt < 4; mt++) {
      const int row_base = bm * 128 + wm * 64 + mt * 16 + quad * 4;
      for (int nt = 0; nt < 4; nt++) {
        const int col = bn * 128 + wn * 64 + nt * 16 + l15;
        const float bb = bias[col];
        for (int r = 0; r < 4; r++) {
          const int row = row_base + r;
          const float v = acc[mt][nt][r] + bb;
          const int b = row >> 11, tt = row & 2047;
          const int h = col >> 6, hi = col & 63;
          const size_t idx = (((size_t)(b * 16 + h)) * 2048 + tt) * 64 + hi;
          if (sel == 0) {
            qbo[idx] = f2b(v);
          } else {
            kf[idx] = v; kbo[idx] = f2b(v);
          }
        }
      }
    }
  } else {
    // V path: f32 out direct; bf16 transpose via LDS (stride 136 shorts).
    short* Tr = SM;                       // 128*136*2 = 34816 B <= 48 KB
    __syncthreads();
    for (int mt = 0; mt < 4; mt++) {
      const int rowb = wm * 64 + mt * 16 + quad * 4;     // local row base
      const int growb = bm * 128 + rowb;
      const int b_ = growb >> 11;
      for (int nt = 0; nt < 4; nt++) {
        const int colL = wn * 64 + nt * 16 + l15;
        const int col = bn * 128 + colL;
        const float bb = bias[col];
        const int h_ = col >> 6, hi_ = col & 63;
        short4 pk;
        for (int r = 0; r < 4; r++) {
          const float v = acc[mt][nt][r] + bb;
          const int tt = (growb + r) & 2047;
          vf[(((size_t)(b_ * 16 + h_)) * 2048 + tt) * 64 + hi_] = v;
          ((short*)&pk)[r] = f2b(v);
        }
        *(short4*)&Tr[colL * 136 + rowb] = pk;
      }
    }
    __syncthreads();
    const int c = t & 127, half = t >> 7;
    const int gcol = bn * 128 + c;
    const int h_ = gcol >> 6, hi_ = gcol & 63;
    for (int j = 0; j < 8; j++) {
      const int chunk = half * 8 + j;
      const int row0 = bm * 128 + chunk * 8;
      const int b_ = row0 >> 11, tt = row0 & 2047;
      bf16x8 val = *(const bf16x8*)&Tr[c * 136 + chunk * 8];
      *(bf16x8*)&vtbo[(((size_t)(b_ * 16 + h_)) * 64 + hi_) * 2048 + tt] = val;
    }
  }
}

// Output projection: C[8192][1024] = attb @ Wo^T + bo, same T4 pipeline.
__global__ __launch_bounds__(256) void gemm_o(
    const short* __restrict__ A, const short* __restrict__ Bm,
    const float* __restrict__ bias, float* __restrict__ out_f) {
  __shared__ short SM[24576];
  const int t = threadIdx.x;
  const int lane = t & 63;
  const int w = t >> 6;
  const int wm = w >> 1, wn = w & 1;
  const int quad = lane >> 4, l15 = lane & 15;
  const int bm = blockIdx.y, bn = blockIdx.x;

  f32x4 acc[4][4];
  for (int i = 0; i < 4; i++)
    for (int j = 0; j < 4; j++) acc[i][j] = (f32x4){0.f, 0.f, 0.f, 0.f};

  const int c0 = t, c1 = t + 256;
  const int r0 = c0 >> 2, cc0 = c0 & 3;
  const int r1 = c1 >> 2, cc1 = c1 & 3;
  const short* Abase = A + (size_t)bm * 128 * 1024;
  const short* Bbase = Bm + (size_t)bn * 128 * 1024;

  auto stage = [&](int buf, int kk) {
    short* A_ = SM + buf * 4096;
    short* B_ = SM + 12288 + buf * 4096;
    GLDS16(Abase + (size_t)r0 * 1024 + kk + cc0 * 8, A_ + c0 * 8);
    GLDS16(Abase + (size_t)r1 * 1024 + kk + cc1 * 8, A_ + c1 * 8);
    GLDS16(Bbase + (size_t)r0 * 1024 + kk + cc0 * 8, B_ + c0 * 8);
    GLDS16(Bbase + (size_t)r1 * 1024 + kk + cc1 * 8, B_ + c1 * 8);
  };
  auto compute = [&](int buf) {
    const short* A_ = SM + buf * 4096;
    const short* B_ = SM + 12288 + buf * 4096;
    bf16x8 af[4], bfr[4];
    for (int mt = 0; mt < 4; mt++)
      af[mt] = *(const bf16x8*)(A_ + (wm * 64 + mt * 16 + l15) * 32 + quad * 8);
    for (int nt = 0; nt < 4; nt++)
      bfr[nt] = *(const bf16x8*)(B_ + (wn * 64 + nt * 16 + l15) * 32 + quad * 8);
    for (int mt = 0; mt < 4; mt++)
      for (int nt = 0; nt < 4; nt++)
        acc[mt][nt] = __builtin_amdgcn_mfma_f32_16x16x32_bf16(af[mt], bfr[nt], acc[mt][nt], 0, 0, 0);
  };

  stage(0, 0);
  stage(1, 32);
  int tile = 0;
  for (int ii = 0; ii < 10; ++ii) {
    PIPE_STEP(0) PIPE_STEP(1) PIPE_STEP(2)
  }
  PIPE_TAIL()

  for (int mt = 0; mt < 4; mt++) {
    const int row_base = bm * 128 + wm * 64 + mt * 16 + quad * 4;
    for (int nt = 0; nt < 4; nt++) {
      const int col = bn * 128 + wn * 64 + nt * 16 + l15;
      const float bb = bias[col];
      for (int r = 0; r < 4; r++) {
        const int row = row_base + r;
        out_f[(size_t)row * 1024 + col] = acc[mt][nt][r] + bb;
      }
    }
  }
}

// Flash attention — the round-4 champion kernel (96 us verified), launched on
// its correct grid dim3(16,64) = 1024 blocks (round-8 regression was a wrong
// dim3(32,64) launch: L-collisions duplicated every strip-pair ~2x).
__global__ __launch_bounds__(256, 4) void attn_fwd(
    const short* __restrict__ Qb, const short* __restrict__ Kb,
    const short* __restrict__ VTb, short* __restrict__ Ob) {
  __shared__ short Ks[128 * 64];        // 16 KB; doubles as per-wave P after QK barrier
  __shared__ short VTs[64 * 128];       // 16 KB
  const int t = threadIdx.x;
  const int w = t >> 6;
  const int lane = t & 63;
  const int quad = lane >> 4, l15 = lane & 15;

  const int L = blockIdx.x + (blockIdx.y << 4);          // 0..1023
  const int work = ((L & 7) << 7) + (L >> 3);            // XCD k -> bh in [8k,8k+8)
  const int bh = work >> 4;
  const int base = work & 15;
  const int b = bh >> 4, h = bh & 15;

  const short* Qh = Qb + (size_t)bh * 2048 * 64;
  const short* Kh = Kb + (size_t)bh * 2048 * 64;
  const short* VTh = VTb + (size_t)bh * 64 * 2048;
  unsigned* Pd = (unsigned*)Ks + w * 1024;               // wave-private 4 KB
  const int swz = (l15 & 7) << 2;
  const float sscale = 0.125f * 1.4426950408889634f;     // hd^-0.5 * log2(e)

  for (int s = 0; s < 2; ++s) {
    const int qt = s ? (31 - base) : base;               // 17 tiles total per block
    const int q0 = qt * 64 + w * 16;
    const bf16x8 qf0 = *(const bf16x8*)(Qh + (q0 + l15) * 64 + quad * 8);
    const bf16x8 qf1 = *(const bf16x8*)(Qh + (q0 + l15) * 64 + quad * 8 + 32);

    float m_q = -1e30f, l_q = 0.f;
    f32x4 o[4];
    for (int nt = 0; nt < 4; nt++) o[nt] = (f32x4){0.f, 0.f, 0.f, 0.f};
    const int ntile = (qt >> 1) + 1;

    for (int jt = 0; jt < ntile; ++jt) {
      const int j0 = jt << 7;
      __syncthreads();   // previous tile's P/PV readers done
      for (int rr = 0; rr < 4; rr++) {
        const int c = rr * 256 + t;
        const int row = c >> 3, colL = c & 7;
        const int colg = colL ^ (row & 7);
        GLDS16(Kh + (size_t)(j0 + row) * 64 + colg * 8, &Ks[c * 8]);
      }
      for (int rr = 0; rr < 4; rr++) {
        const int c = rr * 256 + t;
        const int row = c >> 4, colL = c & 15;
        const int colg = colL ^ (row & 7);
        GLDS16(VTh + (size_t)row * 2048 + j0 + colg * 8, &VTs[c * 8]);
      }
      __syncthreads();   // staging complete (vmcnt drained)

      float sv[8][4];    // RAW scores (scale folded into exp arg later)
      for (int si = 0; si < 8; ++si) {
        const int r = si * 16 + l15;
        bf16x8 kf0 = *(const bf16x8*)&Ks[(r * 8 + (quad ^ (r & 7))) * 8];
        bf16x8 kf1 = *(const bf16x8*)&Ks[(r * 8 + ((quad ^ 4) ^ (r & 7))) * 8];
        f32x4 z = (f32x4){0.f, 0.f, 0.f, 0.f};
        z = __builtin_amdgcn_mfma_f32_16x16x32_bf16(kf0, qf0, z, 0, 0, 0);
        z = __builtin_amdgcn_mfma_f32_16x16x32_bf16(kf1, qf1, z, 0, 0, 0);
        for (int r4 = 0; r4 < 4; r4++) sv[si][r4] = z[r4];
      }
      if (jt == ntile - 1) {                              // diagonal tile masks
        const int qg = q0 + l15;
        for (int si = 0; si < 8; si++) {
          const int kbase = j0 + si * 16 + quad * 4;
          for (int r4 = 0; r4 < 4; r4++)
            if (kbase + r4 > qg) sv[si][r4] = -1e30f;
        }
      }
      float vmax = fmaxf(fmaxf(sv[0][0], sv[0][1]), fmaxf(sv[0][2], sv[0][3]));
      for (int si = 1; si < 8; si++) {
        float m2 = fmaxf(fmaxf(sv[si][0], sv[si][1]), fmaxf(sv[si][2], sv[si][3]));
        vmax = fmaxf(vmax, m2);
      }
      vmax = fmaxf(vmax, __shfl_xor(vmax, 16));
      vmax = fmaxf(vmax, __shfl_xor(vmax, 32));
      const float mn = fmaxf(m_q, vmax);
      if (__any(vmax > m_q)) {           // exact skip: otherwise alpha==1 for all lanes
        const float alpha = __builtin_amdgcn_exp2f((m_q - mn) * sscale);
        l_q *= alpha;
        float ar[4];
        for (int r4 = 0; r4 < 4; r4++) ar[r4] = __shfl(alpha, quad * 4 + r4);
        for (int nt = 0; nt < 4; nt++)
          for (int r4 = 0; r4 < 4; r4++) o[nt][r4] *= ar[r4];
      }
      m_q = mn;
      __syncthreads();   // all waves done reading Ks -> safe to overlay P

      const float negmns = -mn * sscale;
      float ssum = 0.f;
      for (int si = 0; si < 8; si++) {
        float p0 = __builtin_amdgcn_exp2f(fmaf(sv[si][0], sscale, negmns));
        float p1 = __builtin_amdgcn_exp2f(fmaf(sv[si][1], sscale, negmns));
        float p2 = __builtin_amdgcn_exp2f(fmaf(sv[si][2], sscale, negmns));
        float p3 = __builtin_amdgcn_exp2f(fmaf(sv[si][3], sscale, negmns));
        ssum += (p0 + p1) + (p2 + p3);
        uint2 pk; pk.x = cvtpk2(p0, p1); pk.y = cvtpk2(p2, p3);
        *(uint2*)(Pd + l15 * 64 + ((si * 8 + quad * 2) ^ swz)) = pk;
      }
      ssum += __shfl_xor(ssum, 16);
      ssum += __shfl_xor(ssum, 32);
      l_q += ssum;       // alpha already applied inside the rescale branch

      for (int kc = 0; kc < 4; kc++) {
        bf16x8 pf = *(const bf16x8*)(Pd + l15 * 64 + ((kc * 16 + quad * 4) ^ swz));
        for (int nt = 0; nt < 4; nt++) {
          const int rv = nt * 16 + l15;
          bf16x8 vf = *(const bf16x8*)&VTs[(rv * 16 + ((kc * 4 + quad) ^ (rv & 7))) * 8];
          o[nt] = __builtin_amdgcn_mfma_f32_16x16x32_bf16(pf, vf, o[nt], 0, 0, 0);
        }
      }
    }

    float lr[4], ri[4];
    for (int r4 = 0; r4 < 4; r4++) lr[r4] = __shfl(l_q, quad * 4 + r4);
    for (int r4 = 0; r4 < 4; r4++) ri[r4] = __builtin_amdgcn_rcpf(lr[r4]);
    for (int nt = 0; nt < 4; nt++) {
      const int col = h * 64 + nt * 16 + l15;
      for (int r4 = 0; r4 < 4; r4++) {
        const int q = q0 + quad * 4 + r4;
        Ob[((size_t)b * 2048 + q) * 1024 + col] = f2b(o[nt][r4] * ri[r4]);
      }
    }
  }
}

extern "C" void kernel_launch(void* const* d_in, const int* in_sizes, int n_in,
                              void* d_out, int out_size, void* d_ws, size_t ws_size,
                              hipStream_t stream) {
  const float* x  = (const float*)d_in[0];
  const float* Wq = (const float*)d_in[1];
  const float* bq = (const float*)d_in[2];
  const float* Wk = (const float*)d_in[3];
  const float* bk = (const float*)d_in[4];
  const float* Wv = (const float*)d_in[5];
  const float* bv = (const float*)d_in[6];
  const float* Wo = (const float*)d_in[7];
  const float* bo = (const float*)d_in[8];

  float* out   = (float*)d_out;
  float* k_out = out + (size_t)8388608;
  float* v_out = out + (size_t)16777216;

  short* ws  = (short*)d_ws;
  short* xb   = ws;                    // 8388608 elems
  short* wqb  = ws + 8388608;          // 1048576 (wq,wk,wv,wo contiguous)
  short* wkb  = ws + 9437184;
  short* wvb  = ws + 10485760;
  short* wob  = ws + 11534336;
  short* qb   = ws + 12582912;         // 8388608 [B,H,T,64]
  short* kb   = ws + 20971520;         // 8388608 [B,H,T,64]
  short* vtb  = ws + 29360128;         // 8388608 [B,H,64,T]
  short* attb = ws + 37748736;         // 8388608 [B*T,1024]

  cvt_all<<<12288, 256, 0, stream>>>(x, Wq, Wk, Wv, Wo, xb, wqb);

  gemm_qkv<<<dim3(24, 64), 256, 0, stream>>>(
      xb, wqb, wkb, wvb, bq, bk, bv, k_out, v_out, qb, kb, vtb);

  attn_fwd<<<dim3(16, 64), 256, 0, stream>>>(qb, kb, vtb, attb);

  gemm_o<<<dim3(8, 64), 256, 0, stream>>>(attb, wob, bo, out);
}